// Round 14
// baseline (332.319 us; speedup 1.0000x reference)
//
#include <hip/hip_runtime.h>
#include <stdint.h>

#define NTOK 65536     // B*S = 16*4096
#define DMODEL 512
#define QKVN 1536
#define LN_EPS 1e-5f

typedef __attribute__((ext_vector_type(8))) short short8;
typedef __attribute__((ext_vector_type(8))) unsigned short ushort8;
typedef __attribute__((ext_vector_type(4))) float float4_t;
typedef __attribute__((ext_vector_type(4))) unsigned int uint4_t;

static __device__ __forceinline__ float bf2f(unsigned short u) {
    union { unsigned int i; float f; } c; c.i = ((unsigned int)u) << 16; return c.f;
}
static __device__ __forceinline__ unsigned short f2bf(float f) {
    union { float f; unsigned int i; } c; c.f = f;
    unsigned int x = c.i;
    return (unsigned short)((x + 0x7fffu + ((x >> 16) & 1u)) >> 16);  // RNE
}
static __device__ __forceinline__ unsigned int cvt_pk_bf16(float lo, float hi) {
    unsigned int r;
    asm("v_cvt_pk_bf16_f32 %0, %1, %2" : "=v"(r) : "v"(lo), "v"(hi));
    return r;
}
static __device__ __forceinline__ void gload_lds16(const void* g, void* l) {
    __builtin_amdgcn_global_load_lds((const __attribute__((address_space(1))) void*)g,
                                     (__attribute__((address_space(3))) void*)l, 16, 0, 0);
}

#define BAR() __builtin_amdgcn_s_barrier()
#define WAITL0() asm volatile("s_waitcnt lgkmcnt(0)" ::: "memory")
#define WVM(n) asm volatile("s_waitcnt vmcnt(" #n ")" ::: "memory")
#define CFENCE() asm volatile("" ::: "memory")
#define MFMA(a, b, c) __builtin_amdgcn_mfma_f32_16x16x32_bf16((a), (b), (c), 0, 0, 0)

// ---------------------------------------------------------------- prep: weights + bias
// Wqkv: [1536,512] bf16 row-major.  Wpack: Wo in MFMA-fragment order:
// Wpack[((kt*32 + nf)*64 + lane)*8 + e] = Wo[nf*16 + (lane&15)][kt*32 + (lane>>4)*8 + e]
__global__ __launch_bounds__(256) void prep_w_kernel(
    const float* __restrict__ wq, const float* __restrict__ wk, const float* __restrict__ wv,
    const float* __restrict__ wo,
    const float* __restrict__ bq, const float* __restrict__ bk, const float* __restrict__ bv,
    unsigned short* __restrict__ wqkv, unsigned short* __restrict__ wpack,
    float* __restrict__ bias_qkv) {
    const int WN = DMODEL * DMODEL;  // 262144
    int tid = blockIdx.x * blockDim.x + threadIdx.x;
    int stride = gridDim.x * blockDim.x;
    for (int j = tid; j < 3 * WN; j += stride) {
        int seg = j / WN, idx = j - seg * WN;
        const float* src = (seg == 0) ? wq : (seg == 1) ? wk : wv;
        wqkv[j] = f2bf(src[idx]);
    }
    for (int j = tid; j < WN; j += stride) {
        int e = j & 7, l = (j >> 3) & 63, nf = (j >> 9) & 31, kt = j >> 14;
        int row = nf * 16 + (l & 15);
        int k = kt * 32 + ((l >> 4) << 3) + e;
        wpack[j] = f2bf(wo[row * 512 + k]);
    }
    for (int j = tid; j < QKVN; j += stride)
        bias_qkv[j] = (j < 512) ? bq[j] : (j < 1024) ? bk[j - 512] : bv[j - 1024];
}

// ---------------------------------------------------------------- GEMM1: QKV = x @ Wqkv^T + bias
// A = x fp32 read into REGISTERS, converted to bf16 (cvt_pk, RNE) and ds_written
// into the SAME proven bf16 swizzled LDS layout (2 slots, 32 KB).  B stays on the
// counted-vmcnt global_load_lds path (4 slots, 64 KB), distance-2 prefetch.
// 256x256 tile, BK=32, 8 waves (2x4), XCD block swizzle.  Eliminates cast_x.
__global__ __launch_bounds__(512, 2) void gemm1_kernel(
    const float* __restrict__ X, const unsigned short* __restrict__ Bw,
    const float* __restrict__ bias, unsigned short* __restrict__ Cout) {
    __shared__ unsigned short As[2][8192];  // 32 KB bf16 (256 x 32)
    __shared__ unsigned short Bs[4][8192];  // 64 KB bf16

    const int b = blockIdx.x;                   // grid = 1536 = 8 * 192
    const int L = (b & 7) * 192 + (b >> 3);     // bijective XCD swizzle
    const int bm = L / 6;
    const int bn = L - bm * 6;

    const int t = threadIdx.x;
    const int lane = t & 63;
    const int w = t >> 6;
    const int wm = w >> 2, wn = w & 3;          // 2 x 4 waves

    const float* Af = X + (size_t)bm * 256 * 512;
    const unsigned short* Bb = Bw + (size_t)bn * 256 * 512;

    // chunk mapping (shared by A and B): 1024 chunks of 8 elems; thread t owns i0,i1
    const int i0 = t, i1 = 512 + t;
    const int r0 = i0 >> 2, s0 = (i0 & 3) ^ ((r0 >> 1) & 3);
    const int r1 = i1 >> 2, s1 = (i1 & 3) ^ ((r1 >> 1) & 3);

#define STAGE_B1(kt) do { \
        gload_lds16(Bb + r0 * 512 + (kt) * 32 + s0 * 8, &Bs[(kt) & 3][i0 * 8]); \
        gload_lds16(Bb + r1 * 512 + (kt) * 32 + s1 * 8, &Bs[(kt) & 3][i1 * 8]); } while (0)

    // A: issue 4 x 16B fp32 loads into a named register buffer (order-pinned by CFENCE)
#define ISSUE_A(buf, kt) do { \
        const float* p0_ = Af + (size_t)r0 * 512 + (kt) * 32 + s0 * 8; \
        const float* p1_ = Af + (size_t)r1 * 512 + (kt) * 32 + s1 * 8; \
        buf[0] = *(const float4_t*)p0_;       buf[1] = *(const float4_t*)(p0_ + 4); \
        buf[2] = *(const float4_t*)p1_;       buf[3] = *(const float4_t*)(p1_ + 4); \
        CFENCE(); } while (0)

    // A: convert buffer to bf16 and ds_write into slot (kt)&1 (same dest as gload would use)
#define CVTW_A(buf, kt) do { \
        uint4_t w0_, w1_; \
        w0_[0] = cvt_pk_bf16(buf[0][0], buf[0][1]); \
        w0_[1] = cvt_pk_bf16(buf[0][2], buf[0][3]); \
        w0_[2] = cvt_pk_bf16(buf[1][0], buf[1][1]); \
        w0_[3] = cvt_pk_bf16(buf[1][2], buf[1][3]); \
        w1_[0] = cvt_pk_bf16(buf[2][0], buf[2][1]); \
        w1_[1] = cvt_pk_bf16(buf[2][2], buf[2][3]); \
        w1_[2] = cvt_pk_bf16(buf[3][0], buf[3][1]); \
        w1_[3] = cvt_pk_bf16(buf[3][2], buf[3][3]); \
        *(uint4_t*)&As[(kt) & 1][i0 * 8] = w0_; \
        *(uint4_t*)&As[(kt) & 1][i1 * 8] = w1_; } while (0)

    // fragment read offsets (swizzled): p = (lane>>4) ^ ((row>>1)&3)
    int aoff[8], boff[4];
#pragma unroll
    for (int m = 0; m < 8; m++) {
        int row = wm * 128 + m * 16 + (lane & 15);
        aoff[m] = row * 32 + (((lane >> 4) ^ ((row >> 1) & 3)) * 8);
    }
#pragma unroll
    for (int n = 0; n < 4; n++) {
        int row = wn * 64 + n * 16 + (lane & 15);
        boff[n] = row * 32 + (((lane >> 4) ^ ((row >> 1) & 3)) * 8);
    }

    float4_t acc[8][4];
#pragma unroll
    for (int m = 0; m < 8; m++)
#pragma unroll
        for (int n = 0; n < 4; n++) acc[m][n] = (float4_t){0.f, 0.f, 0.f, 0.f};

    float4_t bufE[4], bufO[4];

    // prologue: A(0),B(0),A(1),B(1) issued (order pinned); wait A(0)+B(0) (6 newer remain)
    ISSUE_A(bufE, 0);
    STAGE_B1(0);
    ISSUE_A(bufO, 1);
    STAGE_B1(1);
    WVM(6);
    CVTW_A(bufE, 0);
    WAITL0();   // ds_write of A(0) visible before barrier
    BAR();

    short8 ar[8], br[4];
#pragma unroll
    for (int kt = 0; kt < 16; ++kt) {
        const int slA = kt & 1;
        const int slB = kt & 3;
        // ---- phase 0: read A frags + B n0/n1; issue A(kt+2) regs + B(kt+2) gload; MFMA half 0
#pragma unroll
        for (int m = 0; m < 8; m++) ar[m] = *(const short8*)&As[slA][aoff[m]];
        br[0] = *(const short8*)&Bs[slB][boff[0]];
        br[1] = *(const short8*)&Bs[slB][boff[1]];
        if (kt <= 13) {
            if ((kt & 1) == 0) ISSUE_A(bufE, kt + 2); else ISSUE_A(bufO, kt + 2);
            STAGE_B1(kt + 2);
        }
        BAR();
        WAITL0();
        __builtin_amdgcn_s_setprio(1);
#pragma unroll
        for (int m = 0; m < 8; m++) {
            acc[m][0] = MFMA(ar[m], br[0], acc[m][0]);
            acc[m][1] = MFMA(ar[m], br[1], acc[m][1]);
        }
        __builtin_amdgcn_s_setprio(0);
        BAR();
        // ---- phase 1: read B n2/n3; cvt+ds_write A(kt+1); MFMA half 1; counted vmcnt
        br[2] = *(const short8*)&Bs[slB][boff[2]];
        br[3] = *(const short8*)&Bs[slB][boff[3]];
        if (kt <= 14) {
            // A(kt+1) register readiness is enforced by compiler-inserted waits
            if ((kt & 1) == 0) CVTW_A(bufO, kt + 1); else CVTW_A(bufE, kt + 1);
        }
        BAR();
        WAITL0();   // drains ds_reads for br AND our A ds_writes
        __builtin_amdgcn_s_setprio(1);
#pragma unroll
        for (int m = 0; m < 8; m++) {
            acc[m][2] = MFMA(ar[m], br[2], acc[m][2]);
            acc[m][3] = MFMA(ar[m], br[3], acc[m][3]);
        }
        __builtin_amdgcn_s_setprio(0);
        // B(kt+1) landed: ops issued after it = A(kt+2)x4 + B(kt+2)x2 = 6
        if (kt <= 13) { WVM(6); }
        else if (kt == 14) { WVM(0); }
        BAR();
    }

    // ---- epilogue: C/D mapping col=lane&15, row=(lane>>4)*4+j
    const int orow0 = bm * 256 + wm * 128;
    const int ocol0 = bn * 256 + wn * 64;
#pragma unroll
    for (int m = 0; m < 8; m++) {
#pragma unroll
        for (int n = 0; n < 4; n++) {
            int col = ocol0 + n * 16 + (lane & 15);
            float bv = bias[col];
#pragma unroll
            for (int j = 0; j < 4; j++) {
                int row = orow0 + m * 16 + (lane >> 4) * 4 + j;
                Cout[(size_t)row * QKVN + col] = f2bf(acc[m][n][j] + bv);
            }
        }
    }
#undef STAGE_B1
#undef ISSUE_A
#undef CVTW_A
}

// ---------------------------------------------------------------- FUSED: attention + O-proj + residual + LN
// (R13 variant: 16 tokens/block, 256 threads = 4 waves, 64 KB LDS, QKV burst-staged.)
__global__ __launch_bounds__(256, 2) void attn_o_ln_kernel(
    const unsigned short* __restrict__ qkv, const unsigned short* __restrict__ Wpack,
    const float* __restrict__ bo, const float* __restrict__ xres,
    const float* __restrict__ lng, const float* __restrict__ lnb,
    float* __restrict__ Y) {
    __shared__ __align__(16) unsigned char QKVs[49152];  // 16 rows x 1536 bf16, linear
    __shared__ __align__(16) unsigned char AOs[16384];   // 16 rows x 512 bf16, swizzled
    float* red = (float*)QKVs;                           // overlaid in epilogue

    const int T0 = blockIdx.x * 16;
    const int t = threadIdx.x;
    const int lane = t & 63;
    const int w = t >> 6;        // wave id 0..3 (n-quarter in phase 2)
    const int g = lane >> 4;     // token subgroup / k-slice 0..3
    const int sl = lane & 15;    // dim-slice owner

    // ---------------- step 0: burst-stage QKV tile (wave w -> rows w*4..w*4+3)
#pragma unroll
    for (int j = 0; j < 12; j++) {
        const int row = w * 4 + j / 3;
        const int part = j % 3;
        gload_lds16(qkv + (size_t)(T0 + row) * QKVN + part * 512 + lane * 8,
                    QKVs + row * 3072 + part * 1024 + lane * 16);
    }
    WVM(0);  // wave's own rows landed; no cross-wave dependency yet

    // early B prefetch (retires under attention VALU work)
    const unsigned short* Bb2 = Wpack + ((size_t)(w * 8) * 64 + lane) * 8;
    short8 bA[8], bB[8];
#pragma unroll
    for (int n = 0; n < 8; n++) bA[n] = *(const short8*)(Bb2 + n * 512);
#pragma unroll
    for (int n = 0; n < 8; n++) bB[n] = *(const short8*)(Bb2 + 16384 + n * 512);

    // ---------------- phase 1: per-head attention from LDS (tr = w*4+g)
    const float scale = 0.08838834764831845f;  // 1/sqrt(128)
    {
        const int tr = w * 4 + g;
        const unsigned char* base = QKVs + tr * 3072 + sl * 16;

#pragma unroll
        for (int h = 0; h < 4; h++) {
            short8 qr = *(const short8*)(base + h * 256);
            float qf[8];
#pragma unroll
            for (int d = 0; d < 8; d++) qf[d] = bf2f((unsigned short)qr[d]);
            float s[4];
#pragma unroll
            for (int tt = 0; tt < 4; tt++) {
                short8 kr = *(const short8*)(base + 1024 + tt * 256);
                float a0 = 0.f;
#pragma unroll
                for (int d = 0; d < 8; d++) a0 += qf[d] * bf2f((unsigned short)kr[d]);
                s[tt] = a0;
            }
#pragma unroll
            for (int mask = 1; mask < 16; mask <<= 1)
#pragma unroll
                for (int tt = 0; tt < 4; tt++)
                    s[tt] += __shfl_xor(s[tt], mask, 64);
            float m0 = fmaxf(fmaxf(s[0], s[1]), fmaxf(s[2], s[3])) * scale;
            float p[4];
            float sum = 0.f;
#pragma unroll
            for (int tt = 0; tt < 4; tt++) { p[tt] = __expf(s[tt] * scale - m0); sum += p[tt]; }
            float rr = __frcp_rn(sum);
            float o[8];
#pragma unroll
            for (int d = 0; d < 8; d++) o[d] = 0.f;
#pragma unroll
            for (int tt = 0; tt < 4; tt++) {
                short8 vr = *(const short8*)(base + 2048 + tt * 256);
                float ph = p[tt] * rr;
#pragma unroll
                for (int d = 0; d < 8; d++) o[d] += ph * bf2f((unsigned short)vr[d]);
            }
            uint4_t pk;
            pk[0] = cvt_pk_bf16(o[0], o[1]);
            pk[1] = cvt_pk_bf16(o[2], o[3]);
            pk[2] = cvt_pk_bf16(o[4], o[5]);
            pk[3] = cvt_pk_bf16(o[6], o[7]);
            int off = tr * 1024 + ((h * 256 + sl * 16) ^ ((tr & 7) << 4));
            *(uint4_t*)(AOs + off) = pk;
        }
    }
    __syncthreads();  // AO tile complete (cross-wave reads follow)

    // ---------------- phase 2: [16x512] = AOs @ Wo^T; wave = 1m x 8n;
    // distance-1 pipeline: two named B buffers, 2 kt per iteration.
    const int arow = sl;
    const int aswz = (arow & 7) << 4;

    float4_t acc[8];
#pragma unroll
    for (int n = 0; n < 8; n++) acc[n] = (float4_t){0.f, 0.f, 0.f, 0.f};

#pragma unroll 1
    for (int kt = 0; kt < 16; kt += 2) {
        // even kt: consume bA, prefetch kt+2 into bA
        short8 a0 = *(const short8*)(AOs + arow * 1024 + ((kt * 64 + g * 16) ^ aswz));
#pragma unroll
        for (int n = 0; n < 8; n++) acc[n] = MFMA(a0, bA[n], acc[n]);
        if (kt + 2 < 16) {
#pragma unroll
            for (int n = 0; n < 8; n++)
                bA[n] = *(const short8*)(Bb2 + (size_t)(kt + 2) * 16384 + n * 512);
        }
        // odd kt+1: consume bB, prefetch kt+3 into bB
        short8 a1 = *(const short8*)(AOs + arow * 1024 + (((kt + 1) * 64 + g * 16) ^ aswz));
#pragma unroll
        for (int n = 0; n < 8; n++) acc[n] = MFMA(a1, bB[n], acc[n]);
        if (kt + 3 < 16) {
#pragma unroll
            for (int n = 0; n < 8; n++)
                bB[n] = *(const short8*)(Bb2 + (size_t)(kt + 3) * 16384 + n * 512);
        }
    }
    __syncthreads();  // all QKVs/AOs reads done -> safe to overlay red

    // ---------------- epilogue: bias + residual, LN over the 512-col row, fp32 out
    float bias8[8], gc8[8], bc8[8];
#pragma unroll
    for (int n = 0; n < 8; n++) {
        int c = w * 128 + n * 16 + sl;
        bias8[n] = bo[c]; gc8[n] = lng[c]; bc8[n] = lnb[c];
    }
#pragma unroll
    for (int j = 0; j < 4; j++) {
        int grow = T0 + g * 4 + j;
        const float* xr = xres + (size_t)grow * 512;
#pragma unroll
        for (int n = 0; n < 8; n++)
            acc[n][j] += bias8[n] + xr[w * 128 + n * 16 + sl];
    }
    // per-row partials over this wave's 128 cols; 16-lane butterfly; red[row][w]
#pragma unroll
    for (int j = 0; j < 4; j++) {
        float s = 0.f, s2 = 0.f;
#pragma unroll
        for (int n = 0; n < 8; n++) { float v = acc[n][j]; s += v; s2 += v * v; }
#pragma unroll
        for (int mask = 1; mask < 16; mask <<= 1) {
            s += __shfl_xor(s, mask, 64);
            s2 += __shfl_xor(s2, mask, 64);
        }
        if (sl == 0) {
            int rl = g * 4 + j;
            red[(rl * 4 + w) * 2 + 0] = s;
            red[(rl * 4 + w) * 2 + 1] = s2;
        }
    }
    __syncthreads();
#pragma unroll
    for (int j = 0; j < 4; j++) {
        int rl = g * 4 + j;
        float s = 0.f, s2 = 0.f;
#pragma unroll
        for (int i = 0; i < 4; i++) {
            s += red[(rl * 4 + i) * 2 + 0];
            s2 += red[(rl * 4 + i) * 2 + 1];
        }
        float mu = s * (1.f / 512.f);
        float var = s2 * (1.f / 512.f) - mu * mu;
        float inv = rsqrtf(var + LN_EPS);
        float* yp = Y + (size_t)(T0 + rl) * 512;
#pragma unroll
        for (int n = 0; n < 8; n++) {
            int c = w * 128 + n * 16 + sl;
            yp[c] = (acc[n][j] - mu) * inv * gc8[n] + bc8[n];
        }
    }
}

// ---------------------------------------------------------------- launch
extern "C" void kernel_launch(void* const* d_in, const int* in_sizes, int n_in,
                              void* d_out, int out_size, void* d_ws, size_t ws_size,
                              hipStream_t stream) {
    const float* x   = (const float*)d_in[0];
    const float* wq  = (const float*)d_in[1];
    const float* bq  = (const float*)d_in[2];
    const float* wk  = (const float*)d_in[3];
    const float* bk  = (const float*)d_in[4];
    const float* wv  = (const float*)d_in[5];
    const float* bv  = (const float*)d_in[6];
    const float* wo  = (const float*)d_in[7];
    const float* bo  = (const float*)d_in[8];
    const float* lng = (const float*)d_in[9];
    const float* lnb = (const float*)d_in[10];

    char* ws = (char*)d_ws;
    unsigned short* Wqkv  = (unsigned short*)(ws);                 //   1,572,864  [1536,512] bf16
    unsigned short* Wpack = (unsigned short*)(ws + 1572864);       //     524,288  Wo packed bf16
    float*          Bqkv  = (float*)        (ws + 2097152);        //       6,144  [1536] f32
    unsigned short* QKV   = (unsigned short*)(ws + 2103296);       // 201,326,592  [N,1536] bf16
    float* Y = (float*)d_out;

    prep_w_kernel<<<1024, 256, 0, stream>>>(wq, wk, wv, wo, bq, bk, bv, Wqkv, Wpack, Bqkv);

    // QKV projection: [65536,512] fp32 x (cast fused into reg-staging) @ [1536,512]^T -> bf16
    gemm1_kernel<<<(NTOK / 256) * (QKVN / 256), 512, 0, stream>>>(x, Wqkv, Bqkv, QKV);

    // fused: per-token attention + O-proj + bias + residual + LayerNorm -> fp32 d_out
    attn_o_ln_kernel<<<NTOK / 16, 256, 0, stream>>>(QKV, Wpack, bo, x, lng, lnb, Y);
}

// Round 15
// 320.614 us; speedup vs baseline: 1.0365x; 1.0365x over previous
//
#include <hip/hip_runtime.h>
#include <stdint.h>

#define NTOK 65536     // B*S = 16*4096
#define DMODEL 512
#define QKVN 1536
#define LN_EPS 1e-5f

typedef __attribute__((ext_vector_type(8))) short short8;
typedef __attribute__((ext_vector_type(8))) unsigned short ushort8;
typedef __attribute__((ext_vector_type(4))) float float4_t;
typedef __attribute__((ext_vector_type(4))) unsigned int uint4_t;

static __device__ __forceinline__ float bf2f(unsigned short u) {
    union { unsigned int i; float f; } c; c.i = ((unsigned int)u) << 16; return c.f;
}
static __device__ __forceinline__ unsigned short f2bf(float f) {
    union { float f; unsigned int i; } c; c.f = f;
    unsigned int x = c.i;
    return (unsigned short)((x + 0x7fffu + ((x >> 16) & 1u)) >> 16);  // RNE
}
static __device__ __forceinline__ unsigned int cvt_pk_bf16(float lo, float hi) {
    unsigned int r;
    asm("v_cvt_pk_bf16_f32 %0, %1, %2" : "=v"(r) : "v"(lo), "v"(hi));
    return r;
}
static __device__ __forceinline__ void gload_lds16(const void* g, void* l) {
    __builtin_amdgcn_global_load_lds((const __attribute__((address_space(1))) void*)g,
                                     (__attribute__((address_space(3))) void*)l, 16, 0, 0);
}

#define BAR() __builtin_amdgcn_s_barrier()
#define WAITL0() asm volatile("s_waitcnt lgkmcnt(0)" ::: "memory")
#define WVM(n) asm volatile("s_waitcnt vmcnt(" #n ")" ::: "memory")
#define MFMA(a, b, c) __builtin_amdgcn_mfma_f32_16x16x32_bf16((a), (b), (c), 0, 0, 0)

// ---------------------------------------------------------------- prep: cast x to bf16
__global__ __launch_bounds__(256) void cast_x_kernel(const float* __restrict__ x,
                                                     unsigned short* __restrict__ xb, int n8) {
    int stride = gridDim.x * blockDim.x;
#pragma unroll 2
    for (int i = blockIdx.x * blockDim.x + threadIdx.x; i < n8; i += stride) {
        const float4_t* p = (const float4_t*)(x + (size_t)i * 8);
        float4_t a = p[0], b = p[1];
        ushort8 v;
        v[0] = f2bf(a[0]); v[1] = f2bf(a[1]); v[2] = f2bf(a[2]); v[3] = f2bf(a[3]);
        v[4] = f2bf(b[0]); v[5] = f2bf(b[1]); v[6] = f2bf(b[2]); v[7] = f2bf(b[3]);
        *(ushort8*)(xb + (size_t)i * 8) = v;
    }
}

// ---------------------------------------------------------------- prep: weights + bias
// Wqkv: [1536,512] bf16 row-major.  Wpack: Wo in MFMA-fragment order:
// Wpack[((kt*32 + nf)*64 + lane)*8 + e] = Wo[nf*16 + (lane&15)][kt*32 + (lane>>4)*8 + e]
__global__ __launch_bounds__(256) void prep_w_kernel(
    const float* __restrict__ wq, const float* __restrict__ wk, const float* __restrict__ wv,
    const float* __restrict__ wo,
    const float* __restrict__ bq, const float* __restrict__ bk, const float* __restrict__ bv,
    unsigned short* __restrict__ wqkv, unsigned short* __restrict__ wpack,
    float* __restrict__ bias_qkv) {
    const int WN = DMODEL * DMODEL;  // 262144
    int tid = blockIdx.x * blockDim.x + threadIdx.x;
    int stride = gridDim.x * blockDim.x;
    for (int j = tid; j < 3 * WN; j += stride) {
        int seg = j / WN, idx = j - seg * WN;
        const float* src = (seg == 0) ? wq : (seg == 1) ? wk : wv;
        wqkv[j] = f2bf(src[idx]);
    }
    for (int j = tid; j < WN; j += stride) {
        int e = j & 7, l = (j >> 3) & 63, nf = (j >> 9) & 31, kt = j >> 14;
        int row = nf * 16 + (l & 15);
        int k = kt * 32 + ((l >> 4) << 3) + e;
        wpack[j] = f2bf(wo[row * 512 + k]);
    }
    for (int j = tid; j < QKVN; j += stride)
        bias_qkv[j] = (j < 512) ? bq[j] : (j < 1024) ? bk[j - 512] : bv[j - 1024];
}

// ---------------------------------------------------------------- GEMM1: QKV = Xb @ Wqkv^T + bias
// 256x256 tile, BK=32, 8 waves (2x4), 4-slot circular LDS pipeline (128 KB),
// counted vmcnt (never 0 in steady state), XOR-swizzled LDS, XCD block swizzle.
__global__ __launch_bounds__(512, 2) void gemm1_kernel(
    const unsigned short* __restrict__ A, const unsigned short* __restrict__ Bw,
    const float* __restrict__ bias, unsigned short* __restrict__ Cout) {
    __shared__ unsigned short As[4][256 * 32];  // 64 KB
    __shared__ unsigned short Bs[4][256 * 32];  // 64 KB

    const int b = blockIdx.x;                   // grid = 1536 = 8 * 192
    const int L = (b & 7) * 192 + (b >> 3);     // bijective XCD swizzle
    const int bm = L / 6;
    const int bn = L - bm * 6;

    const int t = threadIdx.x;
    const int lane = t & 63;
    const int w = t >> 6;
    const int wm = w >> 2, wn = w & 3;          // 2 x 4 waves

    const unsigned short* Ab = A + (size_t)bm * 256 * 512;
    const unsigned short* Bb = Bw + (size_t)bn * 256 * 512;

    // staging addressing: LDS linear dest, global source inverse-swizzled
    const int i0 = t, i1 = 512 + t;
    const int r0 = i0 >> 2, s0 = (i0 & 3) ^ ((r0 >> 1) & 3);
    const int r1 = i1 >> 2, s1 = (i1 & 3) ^ ((r1 >> 1) & 3);

#define STAGE_A1(kt) do { \
        gload_lds16(Ab + r0 * 512 + (kt) * 32 + s0 * 8, &As[(kt) & 3][i0 * 8]); \
        gload_lds16(Ab + r1 * 512 + (kt) * 32 + s1 * 8, &As[(kt) & 3][i1 * 8]); } while (0)
#define STAGE_B1(kt) do { \
        gload_lds16(Bb + r0 * 512 + (kt) * 32 + s0 * 8, &Bs[(kt) & 3][i0 * 8]); \
        gload_lds16(Bb + r1 * 512 + (kt) * 32 + s1 * 8, &Bs[(kt) & 3][i1 * 8]); } while (0)

    // fragment read offsets (swizzled): p = (lane>>4) ^ ((row>>1)&3)
    int aoff[8], boff[4];
#pragma unroll
    for (int m = 0; m < 8; m++) {
        int row = wm * 128 + m * 16 + (lane & 15);
        aoff[m] = row * 32 + (((lane >> 4) ^ ((row >> 1) & 3)) * 8);
    }
#pragma unroll
    for (int n = 0; n < 4; n++) {
        int row = wn * 64 + n * 16 + (lane & 15);
        boff[n] = row * 32 + (((lane >> 4) ^ ((row >> 1) & 3)) * 8);
    }

    float4_t acc[8][4];
#pragma unroll
    for (int m = 0; m < 8; m++)
#pragma unroll
        for (int n = 0; n < 4; n++) acc[m][n] = (float4_t){0.f, 0.f, 0.f, 0.f};

    // prologue: stage K-tiles 0,1,2 (12 loads); wait tile 0 (8 remain in flight)
    STAGE_A1(0); STAGE_B1(0);
    STAGE_A1(1); STAGE_B1(1);
    STAGE_A1(2); STAGE_B1(2);
    WVM(8);
    BAR();

    short8 ar[8], br[4];
#pragma unroll
    for (int kt = 0; kt < 16; ++kt) {
        const int sl = kt & 3;
        // ---- phase 0: read A frags + B n0/n1, stage A of kt+3, MFMA n-half 0
#pragma unroll
        for (int m = 0; m < 8; m++) ar[m] = *(const short8*)&As[sl][aoff[m]];
        br[0] = *(const short8*)&Bs[sl][boff[0]];
        br[1] = *(const short8*)&Bs[sl][boff[1]];
        if (kt <= 12) STAGE_A1(kt + 3);
        BAR();
        WAITL0();
        __builtin_amdgcn_s_setprio(1);
#pragma unroll
        for (int m = 0; m < 8; m++) {
            acc[m][0] = MFMA(ar[m], br[0], acc[m][0]);
            acc[m][1] = MFMA(ar[m], br[1], acc[m][1]);
        }
        __builtin_amdgcn_s_setprio(0);
        BAR();
        // ---- phase 1: read B n2/n3, stage B of kt+3, MFMA n-half 1
        br[2] = *(const short8*)&Bs[sl][boff[2]];
        br[3] = *(const short8*)&Bs[sl][boff[3]];
        if (kt <= 12) STAGE_B1(kt + 3);
        BAR();
        WAITL0();
        __builtin_amdgcn_s_setprio(1);
#pragma unroll
        for (int m = 0; m < 8; m++) {
            acc[m][2] = MFMA(ar[m], br[2], acc[m][2]);
            acc[m][3] = MFMA(ar[m], br[3], acc[m][3]);
        }
        __builtin_amdgcn_s_setprio(0);
        // K-tile boundary: ensure tile kt+1 landed; keep 2 tiles (8 loads) in flight
        if (kt <= 12) { WVM(8); }
        else if (kt == 13) { WVM(4); }
        else if (kt == 14) { WVM(0); }
        BAR();
    }

    // ---- epilogue: C/D mapping col=lane&15, row=(lane>>4)*4+j
    const int orow0 = bm * 256 + wm * 128;
    const int ocol0 = bn * 256 + wn * 64;
#pragma unroll
    for (int m = 0; m < 8; m++) {
#pragma unroll
        for (int n = 0; n < 4; n++) {
            int col = ocol0 + n * 16 + (lane & 15);
            float bv = bias[col];
#pragma unroll
            for (int j = 0; j < 4; j++) {
                int row = orow0 + m * 16 + (lane >> 4) * 4 + j;
                Cout[(size_t)row * QKVN + col] = f2bf(acc[m][n][j] + bv);
            }
        }
    }
#undef STAGE_A1
#undef STAGE_B1
}

// ---------------------------------------------------------------- FUSED: attention + O-proj + residual + LN
// (R13 variant: 16 tokens/block, 256 threads = 4 waves, 64 KB LDS, QKV burst-staged.)
__global__ __launch_bounds__(256, 2) void attn_o_ln_kernel(
    const unsigned short* __restrict__ qkv, const unsigned short* __restrict__ Wpack,
    const float* __restrict__ bo, const float* __restrict__ xres,
    const float* __restrict__ lng, const float* __restrict__ lnb,
    float* __restrict__ Y) {
    __shared__ __align__(16) unsigned char QKVs[49152];  // 16 rows x 1536 bf16, linear
    __shared__ __align__(16) unsigned char AOs[16384];   // 16 rows x 512 bf16, swizzled
    float* red = (float*)QKVs;                           // overlaid in epilogue

    const int T0 = blockIdx.x * 16;
    const int t = threadIdx.x;
    const int lane = t & 63;
    const int w = t >> 6;        // wave id 0..3 (n-quarter in phase 2)
    const int g = lane >> 4;     // token subgroup / k-slice 0..3
    const int sl = lane & 15;    // dim-slice owner

    // ---------------- step 0: burst-stage QKV tile (wave w -> rows w*4..w*4+3)
#pragma unroll
    for (int j = 0; j < 12; j++) {
        const int row = w * 4 + j / 3;
        const int part = j % 3;
        gload_lds16(qkv + (size_t)(T0 + row) * QKVN + part * 512 + lane * 8,
                    QKVs + row * 3072 + part * 1024 + lane * 16);
    }
    WVM(0);  // wave's own rows landed; no cross-wave dependency yet

    // early B prefetch (retires under attention VALU work)
    const unsigned short* Bb2 = Wpack + ((size_t)(w * 8) * 64 + lane) * 8;
    short8 bA[8], bB[8];
#pragma unroll
    for (int n = 0; n < 8; n++) bA[n] = *(const short8*)(Bb2 + n * 512);
#pragma unroll
    for (int n = 0; n < 8; n++) bB[n] = *(const short8*)(Bb2 + 16384 + n * 512);

    // ---------------- phase 1: per-head attention from LDS (tr = w*4+g)
    const float scale = 0.08838834764831845f;  // 1/sqrt(128)
    {
        const int tr = w * 4 + g;
        const unsigned char* base = QKVs + tr * 3072 + sl * 16;

#pragma unroll
        for (int h = 0; h < 4; h++) {
            short8 qr = *(const short8*)(base + h * 256);
            float qf[8];
#pragma unroll
            for (int d = 0; d < 8; d++) qf[d] = bf2f((unsigned short)qr[d]);
            float s[4];
#pragma unroll
            for (int tt = 0; tt < 4; tt++) {
                short8 kr = *(const short8*)(base + 1024 + tt * 256);
                float a0 = 0.f;
#pragma unroll
                for (int d = 0; d < 8; d++) a0 += qf[d] * bf2f((unsigned short)kr[d]);
                s[tt] = a0;
            }
#pragma unroll
            for (int mask = 1; mask < 16; mask <<= 1)
#pragma unroll
                for (int tt = 0; tt < 4; tt++)
                    s[tt] += __shfl_xor(s[tt], mask, 64);
            float m0 = fmaxf(fmaxf(s[0], s[1]), fmaxf(s[2], s[3])) * scale;
            float p[4];
            float sum = 0.f;
#pragma unroll
            for (int tt = 0; tt < 4; tt++) { p[tt] = __expf(s[tt] * scale - m0); sum += p[tt]; }
            float rr = __frcp_rn(sum);
            float o[8];
#pragma unroll
            for (int d = 0; d < 8; d++) o[d] = 0.f;
#pragma unroll
            for (int tt = 0; tt < 4; tt++) {
                short8 vr = *(const short8*)(base + 2048 + tt * 256);
                float ph = p[tt] * rr;
#pragma unroll
                for (int d = 0; d < 8; d++) o[d] += ph * bf2f((unsigned short)vr[d]);
            }
            uint4_t pk;
            pk[0] = cvt_pk_bf16(o[0], o[1]);
            pk[1] = cvt_pk_bf16(o[2], o[3]);
            pk[2] = cvt_pk_bf16(o[4], o[5]);
            pk[3] = cvt_pk_bf16(o[6], o[7]);
            int off = tr * 1024 + ((h * 256 + sl * 16) ^ ((tr & 7) << 4));
            *(uint4_t*)(AOs + off) = pk;
        }
    }
    __syncthreads();  // AO tile complete (cross-wave reads follow)

    // ---------------- phase 2: [16x512] = AOs @ Wo^T; wave = 1m x 8n;
    // distance-1 pipeline: two named B buffers, 2 kt per iteration.
    const int arow = sl;
    const int aswz = (arow & 7) << 4;

    float4_t acc[8];
#pragma unroll
    for (int n = 0; n < 8; n++) acc[n] = (float4_t){0.f, 0.f, 0.f, 0.f};

#pragma unroll 1
    for (int kt = 0; kt < 16; kt += 2) {
        // even kt: consume bA, prefetch kt+2 into bA
        short8 a0 = *(const short8*)(AOs + arow * 1024 + ((kt * 64 + g * 16) ^ aswz));
#pragma unroll
        for (int n = 0; n < 8; n++) acc[n] = MFMA(a0, bA[n], acc[n]);
        if (kt + 2 < 16) {
#pragma unroll
            for (int n = 0; n < 8; n++)
                bA[n] = *(const short8*)(Bb2 + (size_t)(kt + 2) * 16384 + n * 512);
        }
        // odd kt+1: consume bB, prefetch kt+3 into bB
        short8 a1 = *(const short8*)(AOs + arow * 1024 + (((kt + 1) * 64 + g * 16) ^ aswz));
#pragma unroll
        for (int n = 0; n < 8; n++) acc[n] = MFMA(a1, bB[n], acc[n]);
        if (kt + 3 < 16) {
#pragma unroll
            for (int n = 0; n < 8; n++)
                bB[n] = *(const short8*)(Bb2 + (size_t)(kt + 3) * 16384 + n * 512);
        }
    }
    __syncthreads();  // all QKVs/AOs reads done -> safe to overlay red

    // ---------------- epilogue: bias + residual, LN over the 512-col row, fp32 out
    float bias8[8], gc8[8], bc8[8];
#pragma unroll
    for (int n = 0; n < 8; n++) {
        int c = w * 128 + n * 16 + sl;
        bias8[n] = bo[c]; gc8[n] = lng[c]; bc8[n] = lnb[c];
    }
#pragma unroll
    for (int j = 0; j < 4; j++) {
        int grow = T0 + g * 4 + j;
        const float* xr = xres + (size_t)grow * 512;
#pragma unroll
        for (int n = 0; n < 8; n++)
            acc[n][j] += bias8[n] + xr[w * 128 + n * 16 + sl];
    }
    // per-row partials over this wave's 128 cols; 16-lane butterfly; red[row][w]
#pragma unroll
    for (int j = 0; j < 4; j++) {
        float s = 0.f, s2 = 0.f;
#pragma unroll
        for (int n = 0; n < 8; n++) { float v = acc[n][j]; s += v; s2 += v * v; }
#pragma unroll
        for (int mask = 1; mask < 16; mask <<= 1) {
            s += __shfl_xor(s, mask, 64);
            s2 += __shfl_xor(s2, mask, 64);
        }
        if (sl == 0) {
            int rl = g * 4 + j;
            red[(rl * 4 + w) * 2 + 0] = s;
            red[(rl * 4 + w) * 2 + 1] = s2;
        }
    }
    __syncthreads();
#pragma unroll
    for (int j = 0; j < 4; j++) {
        int rl = g * 4 + j;
        float s = 0.f, s2 = 0.f;
#pragma unroll
        for (int i = 0; i < 4; i++) {
            s += red[(rl * 4 + i) * 2 + 0];
            s2 += red[(rl * 4 + i) * 2 + 1];
        }
        float mu = s * (1.f / 512.f);
        float var = s2 * (1.f / 512.f) - mu * mu;
        float inv = rsqrtf(var + LN_EPS);
        float* yp = Y + (size_t)(T0 + rl) * 512;
#pragma unroll
        for (int n = 0; n < 8; n++) {
            int c = w * 128 + n * 16 + sl;
            yp[c] = (acc[n][j] - mu) * inv * gc8[n] + bc8[n];
        }
    }
}

// ---------------------------------------------------------------- launch
extern "C" void kernel_launch(void* const* d_in, const int* in_sizes, int n_in,
                              void* d_out, int out_size, void* d_ws, size_t ws_size,
                              hipStream_t stream) {
    const float* x   = (const float*)d_in[0];
    const float* wq  = (const float*)d_in[1];
    const float* bq  = (const float*)d_in[2];
    const float* wk  = (const float*)d_in[3];
    const float* bk  = (const float*)d_in[4];
    const float* wv  = (const float*)d_in[5];
    const float* bv  = (const float*)d_in[6];
    const float* wo  = (const float*)d_in[7];
    const float* bo  = (const float*)d_in[8];
    const float* lng = (const float*)d_in[9];
    const float* lnb = (const float*)d_in[10];

    char* ws = (char*)d_ws;
    unsigned short* Xb    = (unsigned short*)(ws);                 //  67,108,864  x bf16
    unsigned short* Wqkv  = (unsigned short*)(ws + 67108864);      //   1,572,864  [1536,512] bf16
    unsigned short* Wpack = (unsigned short*)(ws + 68681728);      //     524,288  Wo packed bf16
    float*          Bqkv  = (float*)        (ws + 69206016);       //       6,144  [1536] f32
    unsigned short* QKV   = (unsigned short*)(ws + 69212160);      // 201,326,592  [N,1536] bf16
    float* Y = (float*)d_out;

    cast_x_kernel<<<4096, 256, 0, stream>>>(x, Xb, NTOK * 512 / 8);
    prep_w_kernel<<<1024, 256, 0, stream>>>(wq, wk, wv, wo, bq, bk, bv, Wqkv, Wpack, Bqkv);

    // QKV projection: [65536,512] x [1536,512]^T -> bf16 [65536,1536]
    gemm1_kernel<<<(NTOK / 256) * (QKVN / 256), 512, 0, stream>>>(Xb, Wqkv, Bqkv, QKV);

    // fused: per-token attention + O-proj + bias + residual + LayerNorm -> fp32 d_out
    attn_o_ln_kernel<<<NTOK / 16, 256, 0, stream>>>(QKV, Wpack, bo, x, lng, lnb, Y);
}